// Round 4
// baseline (2796.040 us; speedup 1.0000x reference)
//
#include <hip/hip_runtime.h>

// DRL4TSP pointer-network decoder, fully fused single persistent kernel.
// R6: force the 128-VGPR budget via the LDS occupancy lever. R5 counters:
// VGPR_Count STILL 64, WRITE_SIZE still 63 MB -> rW spill persists;
// neither __launch_bounds__(1024,4) nor amdgpu_waves_per_eu(4,4) moved
// the allocator. Root cause theory: the RA's occupancy target comes from
// static LDS: 44 KB -> floor(160/44)=3 -> targets 2 WGs/CU = 8 waves/SIMD
// -> 64-VGPR budget, attributes ignored. Fix: pad static LDS past 80 KB
// (half of 160 KB) so 1 WG/CU is provable -> 16 waves/CU = 4 waves/SIMD
// -> budget 512/4 = 128 regs. HW residency unchanged (grid 256 = 1
// block/CU already): the pad only changes compiler arithmetic. Pad kept
// alive by a runtime-opaque guard (mark[0] > 1e30, never true).
// Everything else byte-identical to R5.
//  - Phase A: 8-way K-split (gg=tid>>3, qq=tid&7), butterfly xor{1,2,4};
//    thread (gg,qq) owns batch qq's LSTM activation for h=gg.
//  - Phase C: wave w = (batch w&7, h-half w>>3); wave pairs merge attn
//    partials via LDS (float2/lane), softmax stays wave-local.
//
// Key algebra (unchanged): with x[b,s] = (static0, static1, load-demand, demand):
//   static_hidden[b,h,s] = W_s[h,:].(x0,x1) + b_s[h]                 (rank-2)
//   base[b,h,s]          = A[h,:].x[b,s] + biasT[h]                  (rank-4)
//   dec@W_ih^T           = G[g,:].(x0,x1)[ptr] + gbias[g]            (rank-2)

#define H 128
#define S 128
#define NBATCH 2048
#define NB 8               // batch elements per block
#define NT 1024            // threads per block (16 waves, 4/SIMD)
#define NBLK (NBATCH / NB) // 256 blocks, 1/CU
#define BS (NBATCH * S)

// h-state LDS layout: quarter-swizzled, stride 36. 8-way 16-float K-slices
// land on 8 distinct bank-quads: conflict-free b128 reads (8-lane broadcast).
#define SHQ 36
#define SHB (4 * SHQ)
#define SHI(bb, h) ((bb) * SHB + (((h) >> 5) * SHQ) + ((h) & 31))
#define QPB 132            // qprime row stride (pad +4, rows 16B-aligned)
#define PADF 10240         // 40 KB LDS pad: total 86016 B > 80 KB -> 1 WG/CU

__device__ __forceinline__ float dot4f(float4 a, float4 b, float c) {
  return fmaf(a.x, b.x, fmaf(a.y, b.y, fmaf(a.z, b.z, fmaf(a.w, b.w, c))));
}
__device__ __forceinline__ float fast_tanh(float x) {
  // tanh(x) = 1 - 2/(e^{2x}+1); overflow->inf->rcp=0->1, underflow->0->-1 (correct)
  float e = __expf(2.f * x);
  float r = __builtin_amdgcn_rcpf(e + 1.f);
  return fmaf(-2.f, r, 1.f);
}
__device__ __forceinline__ float fast_sig(float x) {
  return __builtin_amdgcn_rcpf(1.f + __expf(-x));
}

__global__ __launch_bounds__(NT) __attribute__((amdgpu_waves_per_eu(4, 4)))
void drl4tsp_fused(const float* __restrict__ st, const float* __restrict__ dyn,
                   const float* __restrict__ W_s, const float* __restrict__ b_s,
                   const float* __restrict__ W_ld, const float* __restrict__ b_ld,
                   const float* __restrict__ W_d, const float* __restrict__ b_d,
                   const float* __restrict__ W_ih, const float* __restrict__ b_ih,
                   const float* __restrict__ W_hh, const float* __restrict__ b_hh,
                   const float* __restrict__ W_pd, const float* __restrict__ b_pd,
                   const float* __restrict__ W_pld, const float* __restrict__ b_pld,
                   const float* __restrict__ W_pq, const float* __restrict__ b_pq,
                   const float* __restrict__ W_pr, const float* __restrict__ b_pr,
                   const float* __restrict__ attn_W, const float* __restrict__ mark,
                   float* __restrict__ out)
{
  __shared__ float4 sX[NB][S];     // folded per-(b,s) inputs (x0,x1,l-d,d)   16 KB
  __shared__ float4 sA[H];         // attention rank-4 weights                 2 KB
  __shared__ alignas(16) float sAW[H];   // attn_W                           0.5 KB
  __shared__ float  sQB[H];        // biasT + b_pq                           0.5 KB
  __shared__ float4 sGT4[4][H];    // gate fold (gt0,gt1,gtb,-) per (g,h)      2 KB
  __shared__ float  sH[NB * SHB];  // h-state (quarter-swizzled)             4.5 KB
  __shared__ alignas(16) float sQP[NB * QPB]; // qprime = q + biasT            4 KB
  __shared__ float2 sPart[16][64]; // attn h-half partials per wave            8 KB
  __shared__ float  sSelX0[NB];
  __shared__ float  sSelX1[NB];
  __shared__ float  sPad[PADF];    // 40 KB occupancy governor (never written)

  const int tid = threadIdx.x;
  const int b0  = blockIdx.x * NB;
  const int gg  = tid >> 3, qq = tid & 7;    // matmul: h-row, 8-way K-split
  const int wv  = tid >> 6, lane = tid & 63; // attention
  const int cb  = wv & 7;                    // attention batch
  const int ch  = wv >> 3;                   // attention h-half (0/1)

  // Keep sPad allocated: runtime-opaque guard, mark[0] == 0 in practice.
  if (mark[0] > 1e30f) sPad[tid] = mark[0];

  // ---------------- one-time fold tables & staging ----------------
  // Gate fold for gate-rows (gg, gg+H, gg+2H, gg+3H), computed by qq==0:
  //   gt0[g],gt1[g] = (W_ih@W_s)[row,0..1];  gtb[g] = (W_ih@b_s + b_ih + b_hh)[row]
  if (qq == 0) {
    #pragma unroll
    for (int g = 0; g < 4; ++g) {
      const int row = gg + g * H;
      const float* wr = W_ih + row * H;
      float g0 = 0.f, g1 = 0.f, gb = 0.f;
      for (int h = 0; h < H; h += 4) {
        float4 w   = *(const float4*)(wr + h);
        float4 s01 = *(const float4*)(W_s + 2 * h);
        float4 s23 = *(const float4*)(W_s + 2 * h + 4);
        float4 bs  = *(const float4*)(b_s + h);
        g0 = fmaf(w.x, s01.x, fmaf(w.y, s01.z, fmaf(w.z, s23.x, fmaf(w.w, s23.z, g0))));
        g1 = fmaf(w.x, s01.y, fmaf(w.y, s01.w, fmaf(w.z, s23.y, fmaf(w.w, s23.w, g1))));
        gb = fmaf(w.x, bs.x,  fmaf(w.y, bs.y,  fmaf(w.z, bs.z,  fmaf(w.w, bs.w,  gb))));
      }
      sGT4[g][gg] = make_float4(g0, g1, gb + b_ih[row] + b_hh[row], 0.f);
    }
  }
  if (tid < H) {
    const int h = tid;
    float a0 = 0.f, a1 = 0.f, a2 = 0.f, a3 = 0.f, bt = 0.f;
    for (int j = 0; j < H; ++j) {
      float pr  = W_pr[h * H + j];
      float pld = W_pld[h * H + j];
      float pd  = W_pd[h * H + j];
      float2 wsv = *(const float2*)(W_s + 2 * j);
      float2 wld = *(const float2*)(W_ld + 2 * j);
      float2 wd  = *(const float2*)(W_d + 2 * j);
      a0 = fmaf(pr, wsv.x, a0);
      a1 = fmaf(pr, wsv.y, a1);
      a2 = fmaf(pld, wld.x + wld.y, a2);
      a3 = fmaf(pd,  wd.x + wd.y,  a3);
      bt += pr * b_s[j] + pld * b_ld[j] + pd * b_d[j];
    }
    sA[h]  = make_float4(a0, a1, a2, a3);
    sAW[h] = attn_W[h];
    sQB[h] = bt + b_pr[h] + b_pld[h] + b_pd[h] + b_pq[h];
  }
  {
    int i = tid;                  // NB*S == NT: exactly one element each
    int bb = i >> 7, s = i & (S - 1);
    int go = (b0 + bb) * 2 * S;
    float x0 = st[go + s];
    float x1 = st[go + S + s];
    float ld = dyn[go + s];
    float dm = dyn[go + S + s];
    sX[bb][s] = make_float4(x0, x1, ld - dm, dm);
  }
  for (int i = tid; i < NB * SHB; i += NT) sH[i] = 0.f;
  if (tid < NB) {
    int go = (b0 + tid) * 2 * S;  // dec0 = static_hidden[:,:,0] -> x at s=0
    sSelX0[tid] = st[go + 0];
    sSelX1[tid] = st[go + S + 0];
  }
  if (blockIdx.x == 0 && tid == 0) out[2 * BS] = mark[0];

  // ---- register-resident weights: 8-way K-split slices ----
  float4 rW[4][4];                 // 4 gates x 16-K slice  (64 VGPRs)
  #pragma unroll
  for (int g = 0; g < 4; ++g) {
    const float* wr = W_hh + (gg + g * H) * H + 16 * qq;
    #pragma unroll
    for (int k = 0; k < 4; ++k) rW[g][k] = *(const float4*)(wr + 4 * k);
  }
  float4 rQ[4];                    // W_pq slice            (16 VGPRs)
  {
    const float* wr = W_pq + gg * H + 16 * qq;
    #pragma unroll
    for (int k = 0; k < 4; ++k) rQ[k] = *(const float4*)(wr + 4 * k);
  }
  __syncthreads();

  // ---------------- persistent per-thread setup ----------------
  // 16qq stays inside one 32-float swizzle group: flat per-thread LDS offset.
  const int ofsH = ((qq * 16) >> 5) * SHQ + ((qq * 16) & 31);
  const float qb = sQB[gg];
  float cS = 0.f;                  // c-state for (batch qq, h gg)

  // ---------------- the 128-step decode scan ----------------
  #pragma unroll 1
  for (int t = 0; t < S; ++t) {
    // ---- Phase A: gates = fold(x[ptr]) + h @ W_hh^T ----
    float g4[4] = {0.f, 0.f, 0.f, 0.f};
    #pragma unroll
    for (int bb = 0; bb < NB; ++bb) {
      float a0 = 0.f, a1 = 0.f, a2 = 0.f, a3 = 0.f;
      const float* hp = &sH[bb * SHB + ofsH];
      #pragma unroll
      for (int k = 0; k < 4; ++k) {
        float4 hv = *(const float4*)(hp + 4 * k);
        a0 = dot4f(rW[0][k], hv, a0);
        a1 = dot4f(rW[1][k], hv, a1);
        a2 = dot4f(rW[2][k], hv, a2);
        a3 = dot4f(rW[3][k], hv, a3);
      }
      a0 += __shfl_xor(a0, 1); a0 += __shfl_xor(a0, 2); a0 += __shfl_xor(a0, 4);
      a1 += __shfl_xor(a1, 1); a1 += __shfl_xor(a1, 2); a1 += __shfl_xor(a1, 4);
      a2 += __shfl_xor(a2, 1); a2 += __shfl_xor(a2, 2); a2 += __shfl_xor(a2, 4);
      a3 += __shfl_xor(a3, 1); a3 += __shfl_xor(a3, 2); a3 += __shfl_xor(a3, 4);
      if (qq == bb) { g4[0] = a0; g4[1] = a1; g4[2] = a2; g4[3] = a3; }
    }
    __syncthreads();   // all sH reads done before the h-state update below

    // ---- LSTM activation: this thread owns (batch qq, h gg) ----
    {
      const float x0p = sSelX0[qq], x1p = sSelX1[qq];
      float4 t0 = sGT4[0][gg];
      float4 t1 = sGT4[1][gg];
      float4 t2 = sGT4[2][gg];
      float4 t3 = sGT4[3][gg];
      float gi = g4[0] + fmaf(t0.x, x0p, fmaf(t0.y, x1p, t0.z));
      float gf = g4[1] + fmaf(t1.x, x0p, fmaf(t1.y, x1p, t1.z));
      float gc = g4[2] + fmaf(t2.x, x0p, fmaf(t2.y, x1p, t2.z));
      float go = g4[3] + fmaf(t3.x, x0p, fmaf(t3.y, x1p, t3.z));
      cS = fast_sig(gf) * cS + fast_sig(gi) * fast_tanh(gc);
      sH[SHI(qq, gg)] = fast_sig(go) * fast_tanh(cS);
    }
    __syncthreads();

    // ---- Phase B: qprime = h_new @ W_pq^T + (b_pq + biasT) ----
    {
      float qval = 0.f;
      #pragma unroll
      for (int bb = 0; bb < NB; ++bb) {
        float qa = 0.f;
        const float* hp = &sH[bb * SHB + ofsH];
        #pragma unroll
        for (int k = 0; k < 4; ++k)
          qa = dot4f(rQ[k], *(const float4*)(hp + 4 * k), qa);
        qa += __shfl_xor(qa, 1); qa += __shfl_xor(qa, 2); qa += __shfl_xor(qa, 4);
        if (qq == bb) qval = qa + qb;
      }
      sQP[qq * QPB + gg] = qval;
    }
    __syncthreads();

    // ---- Phase C: attention partials over h-half ch, batch cb ----
    // lane covers s = lane and s = lane+64; h in [64*ch, 64*ch+64)
    float at0 = 0.f, at1 = 0.f;
    {
      const float4 xA = sX[cb][lane];
      const float4 xB = sX[cb][lane + 64];
      const float*  qpp = &sQP[cb * QPB + 64 * ch];
      const float4* sAh = &sA[64 * ch];
      const float*  awp = &sAW[64 * ch];
      #pragma unroll 2
      for (int k = 0; k < 16; ++k) {
        float4 qv = *(const float4*)(qpp + 4 * k);
        float4 aw = *(const float4*)(awp + 4 * k);
        float4 a;
        a = sAh[4 * k + 0];
        { float h0 = dot4f(a, xA, qv.x), h1 = dot4f(a, xB, qv.x);
          at0 = fmaf(aw.x, fast_tanh(h0), at0); at1 = fmaf(aw.x, fast_tanh(h1), at1); }
        a = sAh[4 * k + 1];
        { float h0 = dot4f(a, xA, qv.y), h1 = dot4f(a, xB, qv.y);
          at0 = fmaf(aw.y, fast_tanh(h0), at0); at1 = fmaf(aw.y, fast_tanh(h1), at1); }
        a = sAh[4 * k + 2];
        { float h0 = dot4f(a, xA, qv.z), h1 = dot4f(a, xB, qv.z);
          at0 = fmaf(aw.z, fast_tanh(h0), at0); at1 = fmaf(aw.z, fast_tanh(h1), at1); }
        a = sAh[4 * k + 3];
        { float h0 = dot4f(a, xA, qv.w), h1 = dot4f(a, xB, qv.w);
          at0 = fmaf(aw.w, fast_tanh(h0), at0); at1 = fmaf(aw.w, fast_tanh(h1), at1); }
      }
    }
    sPart[wv][lane] = make_float2(at0, at1);
    __syncthreads();

    // ---- merge h-halves + masked softmax + argmax + select (waves 0..7) ----
    if (wv < 8) {
      float2 o = sPart[wv ^ 8][lane];
      at0 += o.x; at1 += o.y;
      // mask2: +10000 for s>=1, +0 for s==0
      float a0v = at0 + ((lane == 0) ? 0.f : 10000.f);
      float a1v = at1 + 10000.f;
      float v; int idx;
      if (a1v > a0v) { v = a1v; idx = lane + 64; } else { v = a0v; idx = lane; }
      #pragma unroll
      for (int m = 1; m < 64; m <<= 1) {         // lexicographic max: first-occurrence argmax
        float ov = __shfl_xor(v, m);
        int   oi = __shfl_xor(idx, m);
        if (ov > v || (ov == v && oi < idx)) { v = ov; idx = oi; }
      }
      float es = __expf(a0v - v) + __expf(a1v - v);  // max prob = 1/sum(exp(a-max))
      #pragma unroll
      for (int m = 1; m < 64; m <<= 1) es += __shfl_xor(es, m);
      if (lane == 0) {
        const int bg = b0 + cb;
        out[bg * S + t]      = (float)idx;       // tour_idx (B,S)
        out[BS + bg * S + t] = -__logf(es);      // tour_logp (B,S)
        float4 xv = sX[cb][idx];                 // dec_{t+1} = static_hidden[:,:,idx]
        sSelX0[cb] = xv.x;
        sSelX1[cb] = xv.y;
      }
    }
    __syncthreads();
  }
}

extern "C" void kernel_launch(void* const* d_in, const int* in_sizes, int n_in,
                              void* d_out, int out_size, void* d_ws, size_t ws_size,
                              hipStream_t stream) {
  const float* st     = (const float*)d_in[0];
  const float* dyn    = (const float*)d_in[1];
  const float* mark   = (const float*)d_in[2];
  const float* W_s    = (const float*)d_in[3];
  const float* b_s    = (const float*)d_in[4];
  const float* W_ld   = (const float*)d_in[5];
  const float* b_ld   = (const float*)d_in[6];
  const float* W_d    = (const float*)d_in[7];
  const float* b_d    = (const float*)d_in[8];
  const float* W_ih   = (const float*)d_in[9];
  const float* b_ih   = (const float*)d_in[10];
  const float* W_hh   = (const float*)d_in[11];
  const float* b_hh   = (const float*)d_in[12];
  const float* W_pd   = (const float*)d_in[13];
  const float* b_pd   = (const float*)d_in[14];
  const float* W_pld  = (const float*)d_in[15];
  const float* b_pld  = (const float*)d_in[16];
  const float* W_pq   = (const float*)d_in[17];
  const float* b_pq   = (const float*)d_in[18];
  const float* W_pr   = (const float*)d_in[19];
  const float* b_pr   = (const float*)d_in[20];
  const float* attn_W = (const float*)d_in[21];
  float* out = (float*)d_out;

  hipLaunchKernelGGL(drl4tsp_fused, dim3(NBLK), dim3(NT), 0, stream,
                     st, dyn, W_s, b_s, W_ld, b_ld, W_d, b_d, W_ih, b_ih,
                     W_hh, b_hh, W_pd, b_pd, W_pld, b_pld, W_pq, b_pq,
                     W_pr, b_pr, attn_W, mark, out);
}

// Round 5
// 2741.244 us; speedup vs baseline: 1.0200x; 1.0200x over previous
//
#include <hip/hip_runtime.h>

// DRL4TSP pointer-network decoder, fully fused single persistent kernel.
// R7: R6's LDS pad was DCE'd (LDS_Block_Size unchanged 45056) -- a
// non-volatile store to a never-read LDS array is dead code regardless
// of the runtime guard, so the occupancy experiment never ran. The spill
// evidence persists: VGPR_Count 64, WRITE_SIZE 62.7 MB (setup-time rW
// spill, reloaded in-loop on Phase A's critical path).
// Fix: volatile store into the pad (never eliminable -> array must be
// allocated) and pad raised to 48 KB so RAW static LDS = 87.7 KB > 80 KB:
// 1 WG/CU becomes provable -> 16 waves/CU = 4 waves/SIMD -> VGPR budget
// 512/4 = 128. HW residency unchanged (grid 256 = 1 block/CU already);
// the pad only changes the register allocator's occupancy arithmetic.
// Everything else byte-identical to R6.
//  - Phase A: 8-way K-split (gg=tid>>3, qq=tid&7), butterfly xor{1,2,4};
//    thread (gg,qq) owns batch qq's LSTM activation for h=gg.
//  - Phase C: wave w = (batch w&7, h-half w>>3); wave pairs merge attn
//    partials via LDS (float2/lane), softmax stays wave-local.
//
// Key algebra (unchanged): with x[b,s] = (static0, static1, load-demand, demand):
//   static_hidden[b,h,s] = W_s[h,:].(x0,x1) + b_s[h]                 (rank-2)
//   base[b,h,s]          = A[h,:].x[b,s] + biasT[h]                  (rank-4)
//   dec@W_ih^T           = G[g,:].(x0,x1)[ptr] + gbias[g]            (rank-2)

#define H 128
#define S 128
#define NBATCH 2048
#define NB 8               // batch elements per block
#define NT 1024            // threads per block (16 waves, 4/SIMD)
#define NBLK (NBATCH / NB) // 256 blocks, 1/CU
#define BS (NBATCH * S)

// h-state LDS layout: quarter-swizzled, stride 36. 8-way 16-float K-slices
// land on 8 distinct bank-quads: conflict-free b128 reads (8-lane broadcast).
#define SHQ 36
#define SHB (4 * SHQ)
#define SHI(bb, h) ((bb) * SHB + (((h) >> 5) * SHQ) + ((h) & 31))
#define QPB 132            // qprime row stride (pad +4, rows 16B-aligned)
#define PADF 12288         // 48 KB pad: raw static total 87.7 KB > 80 KB -> 1 WG/CU

__device__ __forceinline__ float dot4f(float4 a, float4 b, float c) {
  return fmaf(a.x, b.x, fmaf(a.y, b.y, fmaf(a.z, b.z, fmaf(a.w, b.w, c))));
}
__device__ __forceinline__ float fast_tanh(float x) {
  // tanh(x) = 1 - 2/(e^{2x}+1); overflow->inf->rcp=0->1, underflow->0->-1 (correct)
  float e = __expf(2.f * x);
  float r = __builtin_amdgcn_rcpf(e + 1.f);
  return fmaf(-2.f, r, 1.f);
}
__device__ __forceinline__ float fast_sig(float x) {
  return __builtin_amdgcn_rcpf(1.f + __expf(-x));
}

__global__ __launch_bounds__(NT) __attribute__((amdgpu_waves_per_eu(4, 4)))
void drl4tsp_fused(const float* __restrict__ st, const float* __restrict__ dyn,
                   const float* __restrict__ W_s, const float* __restrict__ b_s,
                   const float* __restrict__ W_ld, const float* __restrict__ b_ld,
                   const float* __restrict__ W_d, const float* __restrict__ b_d,
                   const float* __restrict__ W_ih, const float* __restrict__ b_ih,
                   const float* __restrict__ W_hh, const float* __restrict__ b_hh,
                   const float* __restrict__ W_pd, const float* __restrict__ b_pd,
                   const float* __restrict__ W_pld, const float* __restrict__ b_pld,
                   const float* __restrict__ W_pq, const float* __restrict__ b_pq,
                   const float* __restrict__ W_pr, const float* __restrict__ b_pr,
                   const float* __restrict__ attn_W, const float* __restrict__ mark,
                   float* __restrict__ out)
{
  __shared__ float4 sX[NB][S];     // folded per-(b,s) inputs (x0,x1,l-d,d)   16 KB
  __shared__ float4 sA[H];         // attention rank-4 weights                 2 KB
  __shared__ alignas(16) float sAW[H];   // attn_W                           0.5 KB
  __shared__ float  sQB[H];        // biasT + b_pq                           0.5 KB
  __shared__ float4 sGT4[4][H];    // gate fold (gt0,gt1,gtb,-) per (g,h)      2 KB
  __shared__ float  sH[NB * SHB];  // h-state (quarter-swizzled)             4.5 KB
  __shared__ alignas(16) float sQP[NB * QPB]; // qprime = q + biasT            4 KB
  __shared__ float2 sPart[16][64]; // attn h-half partials per wave            8 KB
  __shared__ float  sSelX0[NB];
  __shared__ float  sSelX1[NB];
  __shared__ float  sPad[PADF];    // 48 KB occupancy governor

  const int tid = threadIdx.x;
  const int b0  = blockIdx.x * NB;
  const int gg  = tid >> 3, qq = tid & 7;    // matmul: h-row, 8-way K-split
  const int wv  = tid >> 6, lane = tid & 63; // attention
  const int cb  = wv & 7;                    // attention batch
  const int ch  = wv >> 3;                   // attention h-half (0/1)

  // Keep sPad allocated: VOLATILE store (never eliminable) behind a
  // runtime-opaque guard; mark[0] == 0 in practice so it never executes.
  if (mark[0] > 1e30f) {
    volatile float* vp = sPad;
    vp[tid] = mark[0];
  }

  // ---------------- one-time fold tables & staging ----------------
  // Gate fold for gate-rows (gg, gg+H, gg+2H, gg+3H), computed by qq==0:
  //   gt0[g],gt1[g] = (W_ih@W_s)[row,0..1];  gtb[g] = (W_ih@b_s + b_ih + b_hh)[row]
  if (qq == 0) {
    #pragma unroll
    for (int g = 0; g < 4; ++g) {
      const int row = gg + g * H;
      const float* wr = W_ih + row * H;
      float g0 = 0.f, g1 = 0.f, gb = 0.f;
      for (int h = 0; h < H; h += 4) {
        float4 w   = *(const float4*)(wr + h);
        float4 s01 = *(const float4*)(W_s + 2 * h);
        float4 s23 = *(const float4*)(W_s + 2 * h + 4);
        float4 bs  = *(const float4*)(b_s + h);
        g0 = fmaf(w.x, s01.x, fmaf(w.y, s01.z, fmaf(w.z, s23.x, fmaf(w.w, s23.z, g0))));
        g1 = fmaf(w.x, s01.y, fmaf(w.y, s01.w, fmaf(w.z, s23.y, fmaf(w.w, s23.w, g1))));
        gb = fmaf(w.x, bs.x,  fmaf(w.y, bs.y,  fmaf(w.z, bs.z,  fmaf(w.w, bs.w,  gb))));
      }
      sGT4[g][gg] = make_float4(g0, g1, gb + b_ih[row] + b_hh[row], 0.f);
    }
  }
  if (tid < H) {
    const int h = tid;
    float a0 = 0.f, a1 = 0.f, a2 = 0.f, a3 = 0.f, bt = 0.f;
    for (int j = 0; j < H; ++j) {
      float pr  = W_pr[h * H + j];
      float pld = W_pld[h * H + j];
      float pd  = W_pd[h * H + j];
      float2 wsv = *(const float2*)(W_s + 2 * j);
      float2 wld = *(const float2*)(W_ld + 2 * j);
      float2 wd  = *(const float2*)(W_d + 2 * j);
      a0 = fmaf(pr, wsv.x, a0);
      a1 = fmaf(pr, wsv.y, a1);
      a2 = fmaf(pld, wld.x + wld.y, a2);
      a3 = fmaf(pd,  wd.x + wd.y,  a3);
      bt += pr * b_s[j] + pld * b_ld[j] + pd * b_d[j];
    }
    sA[h]  = make_float4(a0, a1, a2, a3);
    sAW[h] = attn_W[h];
    sQB[h] = bt + b_pr[h] + b_pld[h] + b_pd[h] + b_pq[h];
  }
  {
    int i = tid;                  // NB*S == NT: exactly one element each
    int bb = i >> 7, s = i & (S - 1);
    int go = (b0 + bb) * 2 * S;
    float x0 = st[go + s];
    float x1 = st[go + S + s];
    float ld = dyn[go + s];
    float dm = dyn[go + S + s];
    sX[bb][s] = make_float4(x0, x1, ld - dm, dm);
  }
  for (int i = tid; i < NB * SHB; i += NT) sH[i] = 0.f;
  if (tid < NB) {
    int go = (b0 + tid) * 2 * S;  // dec0 = static_hidden[:,:,0] -> x at s=0
    sSelX0[tid] = st[go + 0];
    sSelX1[tid] = st[go + S + 0];
  }
  if (blockIdx.x == 0 && tid == 0) out[2 * BS] = mark[0];

  // ---- register-resident weights: 8-way K-split slices ----
  float4 rW[4][4];                 // 4 gates x 16-K slice  (64 VGPRs)
  #pragma unroll
  for (int g = 0; g < 4; ++g) {
    const float* wr = W_hh + (gg + g * H) * H + 16 * qq;
    #pragma unroll
    for (int k = 0; k < 4; ++k) rW[g][k] = *(const float4*)(wr + 4 * k);
  }
  float4 rQ[4];                    // W_pq slice            (16 VGPRs)
  {
    const float* wr = W_pq + gg * H + 16 * qq;
    #pragma unroll
    for (int k = 0; k < 4; ++k) rQ[k] = *(const float4*)(wr + 4 * k);
  }
  __syncthreads();

  // ---------------- persistent per-thread setup ----------------
  // 16qq stays inside one 32-float swizzle group: flat per-thread LDS offset.
  const int ofsH = ((qq * 16) >> 5) * SHQ + ((qq * 16) & 31);
  const float qb = sQB[gg];
  float cS = 0.f;                  // c-state for (batch qq, h gg)

  // ---------------- the 128-step decode scan ----------------
  #pragma unroll 1
  for (int t = 0; t < S; ++t) {
    // ---- Phase A: gates = fold(x[ptr]) + h @ W_hh^T ----
    float g4[4] = {0.f, 0.f, 0.f, 0.f};
    #pragma unroll
    for (int bb = 0; bb < NB; ++bb) {
      float a0 = 0.f, a1 = 0.f, a2 = 0.f, a3 = 0.f;
      const float* hp = &sH[bb * SHB + ofsH];
      #pragma unroll
      for (int k = 0; k < 4; ++k) {
        float4 hv = *(const float4*)(hp + 4 * k);
        a0 = dot4f(rW[0][k], hv, a0);
        a1 = dot4f(rW[1][k], hv, a1);
        a2 = dot4f(rW[2][k], hv, a2);
        a3 = dot4f(rW[3][k], hv, a3);
      }
      a0 += __shfl_xor(a0, 1); a0 += __shfl_xor(a0, 2); a0 += __shfl_xor(a0, 4);
      a1 += __shfl_xor(a1, 1); a1 += __shfl_xor(a1, 2); a1 += __shfl_xor(a1, 4);
      a2 += __shfl_xor(a2, 1); a2 += __shfl_xor(a2, 2); a2 += __shfl_xor(a2, 4);
      a3 += __shfl_xor(a3, 1); a3 += __shfl_xor(a3, 2); a3 += __shfl_xor(a3, 4);
      if (qq == bb) { g4[0] = a0; g4[1] = a1; g4[2] = a2; g4[3] = a3; }
    }
    __syncthreads();   // all sH reads done before the h-state update below

    // ---- LSTM activation: this thread owns (batch qq, h gg) ----
    {
      const float x0p = sSelX0[qq], x1p = sSelX1[qq];
      float4 t0 = sGT4[0][gg];
      float4 t1 = sGT4[1][gg];
      float4 t2 = sGT4[2][gg];
      float4 t3 = sGT4[3][gg];
      float gi = g4[0] + fmaf(t0.x, x0p, fmaf(t0.y, x1p, t0.z));
      float gf = g4[1] + fmaf(t1.x, x0p, fmaf(t1.y, x1p, t1.z));
      float gc = g4[2] + fmaf(t2.x, x0p, fmaf(t2.y, x1p, t2.z));
      float go = g4[3] + fmaf(t3.x, x0p, fmaf(t3.y, x1p, t3.z));
      cS = fast_sig(gf) * cS + fast_sig(gi) * fast_tanh(gc);
      sH[SHI(qq, gg)] = fast_sig(go) * fast_tanh(cS);
    }
    __syncthreads();

    // ---- Phase B: qprime = h_new @ W_pq^T + (b_pq + biasT) ----
    {
      float qval = 0.f;
      #pragma unroll
      for (int bb = 0; bb < NB; ++bb) {
        float qa = 0.f;
        const float* hp = &sH[bb * SHB + ofsH];
        #pragma unroll
        for (int k = 0; k < 4; ++k)
          qa = dot4f(rQ[k], *(const float4*)(hp + 4 * k), qa);
        qa += __shfl_xor(qa, 1); qa += __shfl_xor(qa, 2); qa += __shfl_xor(qa, 4);
        if (qq == bb) qval = qa + qb;
      }
      sQP[qq * QPB + gg] = qval;
    }
    __syncthreads();

    // ---- Phase C: attention partials over h-half ch, batch cb ----
    // lane covers s = lane and s = lane+64; h in [64*ch, 64*ch+64)
    float at0 = 0.f, at1 = 0.f;
    {
      const float4 xA = sX[cb][lane];
      const float4 xB = sX[cb][lane + 64];
      const float*  qpp = &sQP[cb * QPB + 64 * ch];
      const float4* sAh = &sA[64 * ch];
      const float*  awp = &sAW[64 * ch];
      #pragma unroll 2
      for (int k = 0; k < 16; ++k) {
        float4 qv = *(const float4*)(qpp + 4 * k);
        float4 aw = *(const float4*)(awp + 4 * k);
        float4 a;
        a = sAh[4 * k + 0];
        { float h0 = dot4f(a, xA, qv.x), h1 = dot4f(a, xB, qv.x);
          at0 = fmaf(aw.x, fast_tanh(h0), at0); at1 = fmaf(aw.x, fast_tanh(h1), at1); }
        a = sAh[4 * k + 1];
        { float h0 = dot4f(a, xA, qv.y), h1 = dot4f(a, xB, qv.y);
          at0 = fmaf(aw.y, fast_tanh(h0), at0); at1 = fmaf(aw.y, fast_tanh(h1), at1); }
        a = sAh[4 * k + 2];
        { float h0 = dot4f(a, xA, qv.z), h1 = dot4f(a, xB, qv.z);
          at0 = fmaf(aw.z, fast_tanh(h0), at0); at1 = fmaf(aw.z, fast_tanh(h1), at1); }
        a = sAh[4 * k + 3];
        { float h0 = dot4f(a, xA, qv.w), h1 = dot4f(a, xB, qv.w);
          at0 = fmaf(aw.w, fast_tanh(h0), at0); at1 = fmaf(aw.w, fast_tanh(h1), at1); }
      }
    }
    sPart[wv][lane] = make_float2(at0, at1);
    __syncthreads();

    // ---- merge h-halves + masked softmax + argmax + select (waves 0..7) ----
    if (wv < 8) {
      float2 o = sPart[wv ^ 8][lane];
      at0 += o.x; at1 += o.y;
      // mask2: +10000 for s>=1, +0 for s==0
      float a0v = at0 + ((lane == 0) ? 0.f : 10000.f);
      float a1v = at1 + 10000.f;
      float v; int idx;
      if (a1v > a0v) { v = a1v; idx = lane + 64; } else { v = a0v; idx = lane; }
      #pragma unroll
      for (int m = 1; m < 64; m <<= 1) {         // lexicographic max: first-occurrence argmax
        float ov = __shfl_xor(v, m);
        int   oi = __shfl_xor(idx, m);
        if (ov > v || (ov == v && oi < idx)) { v = ov; idx = oi; }
      }
      float es = __expf(a0v - v) + __expf(a1v - v);  // max prob = 1/sum(exp(a-max))
      #pragma unroll
      for (int m = 1; m < 64; m <<= 1) es += __shfl_xor(es, m);
      if (lane == 0) {
        const int bg = b0 + cb;
        out[bg * S + t]      = (float)idx;       // tour_idx (B,S)
        out[BS + bg * S + t] = -__logf(es);      // tour_logp (B,S)
        float4 xv = sX[cb][idx];                 // dec_{t+1} = static_hidden[:,:,idx]
        sSelX0[cb] = xv.x;
        sSelX1[cb] = xv.y;
      }
    }
    __syncthreads();
  }
}

extern "C" void kernel_launch(void* const* d_in, const int* in_sizes, int n_in,
                              void* d_out, int out_size, void* d_ws, size_t ws_size,
                              hipStream_t stream) {
  const float* st     = (const float*)d_in[0];
  const float* dyn    = (const float*)d_in[1];
  const float* mark   = (const float*)d_in[2];
  const float* W_s    = (const float*)d_in[3];
  const float* b_s    = (const float*)d_in[4];
  const float* W_ld   = (const float*)d_in[5];
  const float* b_ld   = (const float*)d_in[6];
  const float* W_d    = (const float*)d_in[7];
  const float* b_d    = (const float*)d_in[8];
  const float* W_ih   = (const float*)d_in[9];
  const float* b_ih   = (const float*)d_in[10];
  const float* W_hh   = (const float*)d_in[11];
  const float* b_hh   = (const float*)d_in[12];
  const float* W_pd   = (const float*)d_in[13];
  const float* b_pd   = (const float*)d_in[14];
  const float* W_pld  = (const float*)d_in[15];
  const float* b_pld  = (const float*)d_in[16];
  const float* W_pq   = (const float*)d_in[17];
  const float* b_pq   = (const float*)d_in[18];
  const float* W_pr   = (const float*)d_in[19];
  const float* b_pr   = (const float*)d_in[20];
  const float* attn_W = (const float*)d_in[21];
  float* out = (float*)d_out;

  hipLaunchKernelGGL(drl4tsp_fused, dim3(NBLK), dim3(NT), 0, stream,
                     st, dyn, W_s, b_s, W_ld, b_ld, W_d, b_d, W_ih, b_ih,
                     W_hh, b_hh, W_pd, b_pd, W_pld, b_pld, W_pq, b_pq,
                     W_pr, b_pr, attn_W, mark, out);
}